// Round 1
// baseline (221.291 us; speedup 1.0000x reference)
//
#include <hip/hip_runtime.h>

// LIF/IF activation, T=4, v_th=1, subtractive reset, ATan surrogate (fwd only).
// out = (sum_{t=1..4} H(v_t - 1)) / 4 * safe_scale, with
//   c = relu(x) / safe_scale;  v <- v + c;  s = H(v-1);  v <- v - s.
// Arithmetic replicated step-by-step in fp32 to match the numpy reference
// bit-for-bit (IEEE division, no reciprocal-multiply: a 1-ulp difference in c
// can flip a spike at a threshold crossing, costing 0.375 absmax).

__device__ __forceinline__ float lif_elem(float x, float safe_scale) {
    float c = fmaxf(x, 0.0f) / safe_scale;   // IEEE-correct fp32 division at -O3 (no fast-math)
    float v = 0.0f;
    float cnt = 0.0f;
#pragma unroll
    for (int t = 0; t < 4; ++t) {
        v += c;
        float s = ((v - 1.0f) >= 0.0f) ? 1.0f : 0.0f;  // H(v - v_th), v_th = 1
        v -= s;
        cnt += s;
    }
    return (cnt * 0.25f) * safe_scale;       // mean over T, then rescale (ref order)
}

__global__ __launch_bounds__(256) void lif_kernel(const float4* __restrict__ x,
                                                  const float* __restrict__ scale_p,
                                                  float4* __restrict__ out,
                                                  int n4) {
    int idx = blockIdx.x * 256 + threadIdx.x;
    if (idx >= n4) return;
    float safe_scale = fmaxf(scale_p[0], 1e-12f);  // scalar, L2-broadcast
    float4 xv = x[idx];
    float4 ov;
    ov.x = lif_elem(xv.x, safe_scale);
    ov.y = lif_elem(xv.y, safe_scale);
    ov.z = lif_elem(xv.z, safe_scale);
    ov.w = lif_elem(xv.w, safe_scale);
    out[idx] = ov;
}

// Tail handler for n % 4 != 0 (not hit for 4096x8192, kept for safety).
__global__ void lif_tail_kernel(const float* __restrict__ x,
                                const float* __restrict__ scale_p,
                                float* __restrict__ out,
                                int start, int n) {
    int idx = start + blockIdx.x * blockDim.x + threadIdx.x;
    if (idx >= n) return;
    float safe_scale = fmaxf(scale_p[0], 1e-12f);
    out[idx] = lif_elem(x[idx], safe_scale);
}

extern "C" void kernel_launch(void* const* d_in, const int* in_sizes, int n_in,
                              void* d_out, int out_size, void* d_ws, size_t ws_size,
                              hipStream_t stream) {
    const float* x = (const float*)d_in[0];
    const float* scale = (const float*)d_in[1];
    float* out = (float*)d_out;
    int n = in_sizes[0];
    int n4 = n >> 2;

    if (n4 > 0) {
        int blocks = (n4 + 255) / 256;
        lif_kernel<<<blocks, 256, 0, stream>>>((const float4*)x, scale,
                                               (float4*)out, n4);
    }
    int tail_start = n4 << 2;
    int tail = n - tail_start;
    if (tail > 0) {
        lif_tail_kernel<<<1, 64, 0, stream>>>(x, scale, out, tail_start, n);
    }
}